// Round 4
// baseline (1143.972 us; speedup 1.0000x reference)
//
#include <hip/hip_runtime.h>
#include <math.h>

#define NN 4096
#define NE 16384
#define NG 64
#define NBLK 512
#define NTHR 256

// ---- ws layout (float offsets) ----
#define OFF_BAR   0        // 32 unsigned barrier counters
#define OFF_DEG   32       // 4096
#define OFF_ST1   4128     // 64
#define OFF_ST2   4192     // 128
#define OFF_ST3   4320     // 256
#define OFF_POOL  4576     // 8192
#define ZERO_FLOATS 12768  // zeroed by memset each call
#define OFF_H1    12768    // 4096*32
#define OFF_H2    143840   // 4096*64
#define OFF_H3    405984   // 4096*128
#define OFF_WX1   930272   // 16*320
#define OFF_WX2   935392   // 32*640
#define OFF_WX3   955872   // 64*1280
#define OFF_Y     1037792  // up to 4096*1152

// ---------------- device-scope grid barrier (fresh counter per use) ----------------
__device__ __forceinline__ void gsync(unsigned* bar, int idx) {
    __syncthreads();
    if (threadIdx.x == 0) {
        __threadfence();   // release prior writes to agent scope
        __hip_atomic_fetch_add(&bar[idx], 1u, __ATOMIC_RELEASE, __HIP_MEMORY_SCOPE_AGENT);
        while (__hip_atomic_load(&bar[idx], __ATOMIC_ACQUIRE, __HIP_MEMORY_SCOPE_AGENT) < (unsigned)NBLK) {}
        __threadfence();   // acquire side
    }
    __syncthreads();
}

// ---------------- phase: build Wext = [We | be | Wr] (K x 10C) + degree ----------------
__device__ __forceinline__ void build_wext(const float* We, const float* be,
                                           const float* Wr, float* Wx,
                                           int CIN, int C, int t) {
    int NC = 10 * C;
    int i = t / NC; int col = t - i * NC;
    float v;
    if (col < 8 * C)      { int f = col / C, o = col - f * C; v = We[f * CIN * C + o * CIN + i]; }
    else if (col < 9 * C) { int o = col - 8 * C;              v = be[o * CIN + i]; }
    else                  { int o = col - 9 * C;              v = Wr[i * C + o]; }
    Wx[t] = v;
}

__device__ void prep_phase(
    const float* We1, const float* be1, const float* Wr1,
    const float* We2, const float* be2, const float* Wr2,
    const float* We3, const float* be3, const float* Wr3,
    const int* ei, float* ws)
{
    int t = blockIdx.x * NTHR + threadIdx.x;
    if (t < 5120)  { build_wext(We1, be1, Wr1, ws + OFF_WX1, 16, 32, t); return; }
    t -= 5120;
    if (t < 20480) { build_wext(We2, be2, Wr2, ws + OFF_WX2, 32, 64, t); return; }
    t -= 20480;
    if (t < 81920) { build_wext(We3, be3, Wr3, ws + OFF_WX3, 64, 128, t); return; }
    t -= 81920;
    if (t < NE)    { atomicAdd(&ws[OFF_DEG + ei[t]], 1.0f); }
}

// ---------------- phase: proj GEMM [Y | h-init] = bn_prelu(A) @ [Wcat | Wr] ----------------
template<int K, int C, bool BN>
__device__ void proj_phase(float* smem,
    const float* __restrict__ A, const float* __restrict__ Bw,
    const float* __restrict__ st, const float* __restrict__ bg,
    const float* __restrict__ bb, const float* __restrict__ alpha,
    const float* __restrict__ bias, const float* __restrict__ br,
    float* __restrict__ Y, float* __restrict__ h)
{
    constexpr int NC = 10 * C;
    constexpr int TN = NC / 64;
    float* sA = smem;                 // [K][68]
    float* sB = smem + K * 68;        // [K][68]
    float* sS = smem + 2 * K * 68;    // [K]
    float* sT = sS + K;               // [K]
    const int tid = threadIdx.x;
    float al = BN ? alpha[0] : 0.f;

    if constexpr (BN) {
        if (tid < K) {
            float mean = st[tid] * (1.f / NN);
            float var  = st[K + tid] * (1.f / NN) - mean * mean;
            var = fmaxf(var, 0.f);
            float s = rsqrtf(var + 1e-5f) * bg[tid];
            sS[tid] = s; sT[tid] = bb[tid] - mean * s;
        }
    }

    for (int t = blockIdx.x; t < 64 * TN; t += NBLK) {
        __syncthreads();              // smem WAR across tiles/phases
        const int m0 = (t % 64) * 64;
        const int n0 = (t / 64) * 64;
        for (int u = tid; u < 64 * K; u += NTHR) {
            int m = u / K, i = u - m * K;
            float v = A[(m0 + m) * K + i];
            if constexpr (BN) { v = sS[i] * v + sT[i]; v = v >= 0.f ? v : al * v; }
            sA[i * 68 + m] = v;
        }
        for (int u = tid; u < 64 * K; u += NTHR) {
            int i = u / 64, n = u - i * 64;
            sB[i * 68 + n] = Bw[i * NC + n0 + n];
        }
        __syncthreads();

        const int tn = tid % 16, tm = tid / 16;
        float acc[4][4] = {{0.f}};
#pragma unroll 8
        for (int i = 0; i < K; ++i) {
            float4 a = *(const float4*)&sA[i * 68 + tm * 4];
            float4 b = *(const float4*)&sB[i * 68 + tn * 4];
            acc[0][0] += a.x * b.x; acc[0][1] += a.x * b.y; acc[0][2] += a.x * b.z; acc[0][3] += a.x * b.w;
            acc[1][0] += a.y * b.x; acc[1][1] += a.y * b.y; acc[1][2] += a.y * b.z; acc[1][3] += a.y * b.w;
            acc[2][0] += a.z * b.x; acc[2][1] += a.z * b.y; acc[2][2] += a.z * b.z; acc[2][3] += a.z * b.w;
            acc[3][0] += a.w * b.x; acc[3][1] += a.w * b.y; acc[3][2] += a.w * b.z; acc[3][3] += a.w * b.w;
        }

        if (n0 + 64 <= 9 * C) {            // pure-Y block
#pragma unroll
            for (int mm = 0; mm < 4; ++mm) {
                int m = m0 + tm * 4 + mm;
                float4 v = make_float4(acc[mm][0], acc[mm][1], acc[mm][2], acc[mm][3]);
                *(float4*)&Y[(size_t)m * (9 * C) + n0 + tn * 4] = v;
            }
        } else if (n0 >= 9 * C) {          // pure-residual block: init h
            int o = n0 - 9 * C + tn * 4;
            float4 add = *(const float4*)&bias[o];
            float4 ad2 = *(const float4*)&br[o];
#pragma unroll
            for (int mm = 0; mm < 4; ++mm) {
                int m = m0 + tm * 4 + mm;
                float4 v = make_float4(acc[mm][0] + add.x + ad2.x, acc[mm][1] + add.y + ad2.y,
                                       acc[mm][2] + add.z + ad2.z, acc[mm][3] + add.w + ad2.w);
                *(float4*)&h[(size_t)m * C + o] = v;
            }
        } else {                           // mixed block (C=32 only)
#pragma unroll
            for (int mm = 0; mm < 4; ++mm) {
                int m = m0 + tm * 4 + mm;
#pragma unroll
                for (int nn = 0; nn < 4; ++nn) {
                    int col = n0 + tn * 4 + nn;
                    if (col < 9 * C) Y[(size_t)m * (9 * C) + col] = acc[mm][nn];
                    else { int o = col - 9 * C; h[(size_t)m * C + o] = acc[mm][nn] + bias[o] + br[o]; }
                }
            }
        }
    }
}

// ---------------- phase: per-edge float4 gather + scatter-atomics ----------------
template<int C>
__device__ void egather_phase(
    const float* __restrict__ Y, const float* __restrict__ eattr,
    const int* __restrict__ ei, const float* __restrict__ deg,
    float* __restrict__ h)
{
    constexpr int Q = C / 4;
    for (int idx = blockIdx.x * NTHR + threadIdx.x; idx < NE * Q; idx += NBLK * NTHR) {
        int e = idx / Q;
        int q = idx - e * Q;
        int src = ei[e], dst = ei[NE + e];
        float d = deg[src];
        float nrm = d > 0.f ? 1.f / d : 0.f;
        const float4* y = (const float4*)(Y + (size_t)src * (9 * C));
        const float* ea = eattr + e * 8;
        float4 acc = y[8 * Q + q];      // be-term (ea'=1)
#pragma unroll
        for (int f = 0; f < 8; ++f) {
            float4 yf = y[f * Q + q];
            float w = ea[f];
            acc.x += w * yf.x; acc.y += w * yf.y; acc.z += w * yf.z; acc.w += w * yf.w;
        }
        float* hp = h + (size_t)dst * C + q * 4;
        atomicAdd(hp + 0, acc.x * nrm);
        atomicAdd(hp + 1, acc.y * nrm);
        atomicAdd(hp + 2, acc.z * nrm);
        atomicAdd(hp + 3, acc.w * nrm);
    }
}

// ---------------- phase: BN stats (sum / sumsq per channel) ----------------
template<int C>
__device__ void bnstat_phase(float* smem, const float* __restrict__ h, float* __restrict__ st)
{
    if (blockIdx.x >= 64) return;
    constexpr int NL = 256 / C;
    float* sred = smem;
    const int tid = threadIdx.x;
    const int o = tid % C, nl = tid / C;
    const int rbase = blockIdx.x * 64;
    float sum = 0.f, sq = 0.f;
    for (int r = nl; r < 64; r += NL) {
        float v = h[(size_t)(rbase + r) * C + o];
        sum += v; sq += v * v;
    }
    sred[tid] = sum;
    __syncthreads();
    if (tid < C) {
        float s = 0.f;
        for (int g2 = 0; g2 < NL; ++g2) s += sred[g2 * C + tid];
        atomicAdd(&st[tid], s);
    }
    __syncthreads();
    sred[tid] = sq;
    __syncthreads();
    if (tid < C) {
        float s = 0.f;
        for (int g2 = 0; g2 < NL; ++g2) s += sred[g2 * C + tid];
        atomicAdd(&st[C + tid], s);
    }
}

// ---------------- phase: gated pooling (BN3+PReLU folded) ----------------
__device__ void pool_phase(float* smem,
    const float* __restrict__ h3, const int* __restrict__ batch,
    const float* __restrict__ st, const float* __restrict__ bg,
    const float* __restrict__ bb, const float* __restrict__ alpha,
    const float* __restrict__ Wi, const float* __restrict__ bi,
    const float* __restrict__ Wj, const float* __restrict__ bj,
    float* __restrict__ pooled)
{
    if (blockIdx.x >= NN / 16) return;
    constexpr int KN = 8, NB = 16;
    float* sH = smem;                  // 2048
    float* sS = smem + 2048;           // 128
    float* sT = smem + 2176;           // 128
    int*   sB = (int*)(smem + 2304);   // 16
    const int tid = threadIdx.x;
    const int nbase = blockIdx.x * NB;
    if (tid < 128) {
        float mean = st[tid] * (1.f / NN);
        float var  = st[128 + tid] * (1.f / NN) - mean * mean;
        var = fmaxf(var, 0.f);
        float s = rsqrtf(var + 1e-5f) * bg[tid];
        sS[tid] = s; sT[tid] = bb[tid] - mean * s;
    }
    float al = alpha[0];
    __syncthreads();
    for (int t = tid; t < NB * 128; t += NTHR) {
        int i = t % 128;
        float v = sS[i] * h3[(size_t)nbase * 128 + t] + sT[i];
        sH[t] = v >= 0.f ? v : al * v;
    }
    if (tid < NB) sB[tid] = batch[nbase + tid];
    __syncthreads();

    const int o = tid % 128, nl = tid / 128;
    float gacc[KN], facc[KN];
#pragma unroll
    for (int k = 0; k < KN; ++k) { gacc[k] = 0.f; facc[k] = 0.f; }
    for (int i = 0; i < 128; ++i) {
        float wi = Wi[i * 128 + o], wj = Wj[i * 128 + o];
#pragma unroll
        for (int k = 0; k < KN; ++k) {
            float hv = sH[(nl * KN + k) * 128 + i];
            gacc[k] += hv * wi;
            facc[k] += hv * wj;
        }
    }
    float bio = bi[o], bjo = bj[o];
#pragma unroll
    for (int k = 0; k < KN; ++k) {
        int r = nl * KN + k;
        float gate = 1.f / (1.f + expf(-(gacc[k] + bio)));
        float feat = tanhf(facc[k] + bjo);
        atomicAdd(&pooled[sB[r] * 128 + o], gate * feat);
    }
}

// ---------------- phase: final head ----------------
__device__ void final_phase(float* smem,
    const float* __restrict__ pooled, const float* __restrict__ Wfc,
    const float* __restrict__ bfc, float* __restrict__ out)
{
    if (blockIdx.x >= NG) return;
    float* sP = smem;
    const int g = blockIdx.x, c = threadIdx.x;
    if (c < 128) sP[c] = tanhf(pooled[g * 128 + c]);
    __syncthreads();
    float z = bfc[c];
    for (int i = 0; i < 128; ++i) z += sP[i] * Wfc[i * 256 + c];
    int oidx = (c < 128) ? (g * 128 + c) : (NG * 128 + g * 128 + (c - 128));
    out[oidx] = z;
}

// ---------------- the megakernel ----------------
__global__ __launch_bounds__(NTHR, 2) void k_mega(
    const float* __restrict__ x, const float* __restrict__ eattr,
    const int* __restrict__ ei, const int* __restrict__ batch,
    const float* We1, const float* be1, const float* bias1, const float* Wr1, const float* br1,
    const float* bg1, const float* bb1, const float* a1,
    const float* We2, const float* be2, const float* bias2, const float* Wr2, const float* br2,
    const float* bg2, const float* bb2, const float* a2,
    const float* We3, const float* be3, const float* bias3, const float* Wr3, const float* br3,
    const float* bg3, const float* bb3, const float* a3,
    const float* Wi, const float* bi, const float* Wj, const float* bj,
    const float* Wfc, const float* bfc,
    float* __restrict__ ws, float* __restrict__ out)
{
    __shared__ float smem[8832];   // 35.3 KB arena shared by all phases
    unsigned* bar = (unsigned*)(ws + OFF_BAR);

    prep_phase(We1, be1, Wr1, We2, be2, Wr2, We3, be3, Wr3, ei, ws);
    gsync(bar, 0);
    proj_phase<16, 32, false>(smem, x, ws + OFF_WX1, nullptr, nullptr, nullptr, nullptr,
                              bias1, br1, ws + OFF_Y, ws + OFF_H1);
    gsync(bar, 1);
    egather_phase<32>(ws + OFF_Y, eattr, ei, ws + OFF_DEG, ws + OFF_H1);
    gsync(bar, 2);
    bnstat_phase<32>(smem, ws + OFF_H1, ws + OFF_ST1);
    gsync(bar, 3);
    proj_phase<32, 64, true>(smem, ws + OFF_H1, ws + OFF_WX2, ws + OFF_ST1, bg1, bb1, a1,
                             bias2, br2, ws + OFF_Y, ws + OFF_H2);
    gsync(bar, 4);
    egather_phase<64>(ws + OFF_Y, eattr, ei, ws + OFF_DEG, ws + OFF_H2);
    gsync(bar, 5);
    bnstat_phase<64>(smem, ws + OFF_H2, ws + OFF_ST2);
    gsync(bar, 6);
    proj_phase<64, 128, true>(smem, ws + OFF_H2, ws + OFF_WX3, ws + OFF_ST2, bg2, bb2, a2,
                              bias3, br3, ws + OFF_Y, ws + OFF_H3);
    gsync(bar, 7);
    egather_phase<128>(ws + OFF_Y, eattr, ei, ws + OFF_DEG, ws + OFF_H3);
    gsync(bar, 8);
    bnstat_phase<128>(smem, ws + OFF_H3, ws + OFF_ST3);
    gsync(bar, 9);
    pool_phase(smem, ws + OFF_H3, batch, ws + OFF_ST3, bg3, bb3, a3, Wi, bi, Wj, bj, ws + OFF_POOL);
    gsync(bar, 10);
    final_phase(smem, ws + OFF_POOL, Wfc, bfc, out);
}

extern "C" void kernel_launch(void* const* d_in, const int* in_sizes, int n_in,
                              void* d_out, int out_size, void* d_ws, size_t ws_size,
                              hipStream_t stream)
{
    (void)in_sizes; (void)n_in; (void)out_size; (void)ws_size;
    const float* x     = (const float*)d_in[0];
    const float* eattr = (const float*)d_in[1];
    const int*   ei    = (const int*)d_in[2];
    const int*   batch = (const int*)d_in[3];
    const float* We1 = (const float*)d_in[4];
    const float* be1 = (const float*)d_in[5];
    const float* bias1 = (const float*)d_in[6];
    const float* Wr1 = (const float*)d_in[7];
    const float* br1 = (const float*)d_in[8];
    const float* bg1 = (const float*)d_in[9];
    const float* bb1 = (const float*)d_in[10];
    const float* a1  = (const float*)d_in[11];
    const float* We2 = (const float*)d_in[12];
    const float* be2 = (const float*)d_in[13];
    const float* bias2 = (const float*)d_in[14];
    const float* Wr2 = (const float*)d_in[15];
    const float* br2 = (const float*)d_in[16];
    const float* bg2 = (const float*)d_in[17];
    const float* bb2 = (const float*)d_in[18];
    const float* a2  = (const float*)d_in[19];
    const float* We3 = (const float*)d_in[20];
    const float* be3 = (const float*)d_in[21];
    const float* bias3 = (const float*)d_in[22];
    const float* Wr3 = (const float*)d_in[23];
    const float* br3 = (const float*)d_in[24];
    const float* bg3 = (const float*)d_in[25];
    const float* bb3 = (const float*)d_in[26];
    const float* a3  = (const float*)d_in[27];
    const float* Wi  = (const float*)d_in[28];
    const float* bi  = (const float*)d_in[29];
    const float* Wj  = (const float*)d_in[30];
    const float* bj  = (const float*)d_in[31];
    const float* Wfc = (const float*)d_in[32];
    const float* bfc = (const float*)d_in[33];
    float* ws  = (float*)d_ws;
    float* out = (float*)d_out;

    hipMemsetAsync(d_ws, 0, (size_t)ZERO_FLOATS * sizeof(float), stream);
    k_mega<<<NBLK, NTHR, 0, stream>>>(
        x, eattr, ei, batch,
        We1, be1, bias1, Wr1, br1, bg1, bb1, a1,
        We2, be2, bias2, Wr2, br2, bg2, bb2, a2,
        We3, be3, bias3, Wr3, br3, bg3, bb3, a3,
        Wi, bi, Wj, bj, Wfc, bfc, ws, out);
}

// Round 5
// 725.084 us; speedup vs baseline: 1.5777x; 1.5777x over previous
//
#include <hip/hip_runtime.h>
#include <math.h>

#define NN 4096
#define NE 16384
#define NG 64
#define NBLK 512
#define NTHR 256

// ---- ws layout (float offsets) ----
#define OFF_BAR   0        // 32 unsigned barrier counters
#define OFF_DEG   32       // 4096
#define OFF_ST1   4128     // 64
#define OFF_ST2   4192     // 128
#define OFF_ST3   4320     // 256
#define OFF_POOL  4576     // 8192
#define ZERO_FLOATS 12768  // zeroed by memset each call
#define OFF_H1    12768    // 4096*32
#define OFF_H2    143840   // 4096*64
#define OFF_H3    405984   // 4096*128
#define OFF_WX1   930272   // 16*320
#define OFF_WX2   935392   // 32*640
#define OFF_WX3   955872   // 64*1280
#define OFF_Y     1037792  // up to 4096*1152

// ---------------- device-scope grid barrier ----------------
// Arrival: release fence + RELAXED fetch_add. Poll: RELAXED load + s_sleep
// backoff (NO acquire in the loop -- an acquire load invalidates L1 every
// poll iteration on gfx950, which was R4's 90us/barrier storm). One acquire
// fence after the condition is observed.
__device__ __forceinline__ void gsync(unsigned* bar, int idx) {
    __syncthreads();
    if (threadIdx.x == 0) {
        __threadfence();   // release prior writes to agent scope
        __hip_atomic_fetch_add(&bar[idx], 1u, __ATOMIC_RELAXED, __HIP_MEMORY_SCOPE_AGENT);
        while (__hip_atomic_load(&bar[idx], __ATOMIC_RELAXED, __HIP_MEMORY_SCOPE_AGENT) < (unsigned)NBLK)
            __builtin_amdgcn_s_sleep(8);
        __threadfence();   // acquire side
    }
    __syncthreads();
}

// ---------------- phase: build Wext = [We | be | Wr] (K x 10C) + degree ----------------
__device__ __forceinline__ void build_wext(const float* We, const float* be,
                                           const float* Wr, float* Wx,
                                           int CIN, int C, int t) {
    int NC = 10 * C;
    int i = t / NC; int col = t - i * NC;
    float v;
    if (col < 8 * C)      { int f = col / C, o = col - f * C; v = We[f * CIN * C + o * CIN + i]; }
    else if (col < 9 * C) { int o = col - 8 * C;              v = be[o * CIN + i]; }
    else                  { int o = col - 9 * C;              v = Wr[i * C + o]; }
    Wx[t] = v;
}

__device__ void prep_phase(
    const float* We1, const float* be1, const float* Wr1,
    const float* We2, const float* be2, const float* Wr2,
    const float* We3, const float* be3, const float* Wr3,
    const int* ei, float* ws)
{
    int t = blockIdx.x * NTHR + threadIdx.x;
    if (t < 5120)  { build_wext(We1, be1, Wr1, ws + OFF_WX1, 16, 32, t); return; }
    t -= 5120;
    if (t < 20480) { build_wext(We2, be2, Wr2, ws + OFF_WX2, 32, 64, t); return; }
    t -= 20480;
    if (t < 81920) { build_wext(We3, be3, Wr3, ws + OFF_WX3, 64, 128, t); return; }
    t -= 81920;
    if (t < NE)    { atomicAdd(&ws[OFF_DEG + ei[t]], 1.0f); }
}

// ---------------- phase: proj GEMM [Y | h-init] = bn_prelu(A) @ [Wcat | Wr] ----------------
template<int K, int C, bool BN>
__device__ void proj_phase(float* smem,
    const float* __restrict__ A, const float* __restrict__ Bw,
    const float* __restrict__ st, const float* __restrict__ bg,
    const float* __restrict__ bb, const float* __restrict__ alpha,
    const float* __restrict__ bias, const float* __restrict__ br,
    float* __restrict__ Y, float* __restrict__ h)
{
    constexpr int NC = 10 * C;
    constexpr int TN = NC / 64;
    float* sA = smem;                 // [K][68]
    float* sB = smem + K * 68;        // [K][68]
    float* sS = smem + 2 * K * 68;    // [K]
    float* sT = sS + K;               // [K]
    const int tid = threadIdx.x;
    float al = BN ? alpha[0] : 0.f;

    if constexpr (BN) {
        if (tid < K) {
            float mean = st[tid] * (1.f / NN);
            float var  = st[K + tid] * (1.f / NN) - mean * mean;
            var = fmaxf(var, 0.f);
            float s = rsqrtf(var + 1e-5f) * bg[tid];
            sS[tid] = s; sT[tid] = bb[tid] - mean * s;
        }
    }

    for (int t = blockIdx.x; t < 64 * TN; t += NBLK) {
        __syncthreads();              // smem WAR across tiles/phases
        const int m0 = (t % 64) * 64;
        const int n0 = (t / 64) * 64;
        for (int u = tid; u < 64 * K; u += NTHR) {
            int m = u / K, i = u - m * K;
            float v = A[(m0 + m) * K + i];
            if constexpr (BN) { v = sS[i] * v + sT[i]; v = v >= 0.f ? v : al * v; }
            sA[i * 68 + m] = v;
        }
        for (int u = tid; u < 64 * K; u += NTHR) {
            int i = u / 64, n = u - i * 64;
            sB[i * 68 + n] = Bw[i * NC + n0 + n];
        }
        __syncthreads();

        const int tn = tid % 16, tm = tid / 16;
        float acc[4][4] = {{0.f}};
#pragma unroll 8
        for (int i = 0; i < K; ++i) {
            float4 a = *(const float4*)&sA[i * 68 + tm * 4];
            float4 b = *(const float4*)&sB[i * 68 + tn * 4];
            acc[0][0] += a.x * b.x; acc[0][1] += a.x * b.y; acc[0][2] += a.x * b.z; acc[0][3] += a.x * b.w;
            acc[1][0] += a.y * b.x; acc[1][1] += a.y * b.y; acc[1][2] += a.y * b.z; acc[1][3] += a.y * b.w;
            acc[2][0] += a.z * b.x; acc[2][1] += a.z * b.y; acc[2][2] += a.z * b.z; acc[2][3] += a.z * b.w;
            acc[3][0] += a.w * b.x; acc[3][1] += a.w * b.y; acc[3][2] += a.w * b.z; acc[3][3] += a.w * b.w;
        }

        if (n0 + 64 <= 9 * C) {            // pure-Y block
#pragma unroll
            for (int mm = 0; mm < 4; ++mm) {
                int m = m0 + tm * 4 + mm;
                float4 v = make_float4(acc[mm][0], acc[mm][1], acc[mm][2], acc[mm][3]);
                *(float4*)&Y[(size_t)m * (9 * C) + n0 + tn * 4] = v;
            }
        } else if (n0 >= 9 * C) {          // pure-residual block: init h
            int o = n0 - 9 * C + tn * 4;
            float4 add = *(const float4*)&bias[o];
            float4 ad2 = *(const float4*)&br[o];
#pragma unroll
            for (int mm = 0; mm < 4; ++mm) {
                int m = m0 + tm * 4 + mm;
                float4 v = make_float4(acc[mm][0] + add.x + ad2.x, acc[mm][1] + add.y + ad2.y,
                                       acc[mm][2] + add.z + ad2.z, acc[mm][3] + add.w + ad2.w);
                *(float4*)&h[(size_t)m * C + o] = v;
            }
        } else {                           // mixed block (C=32 only)
#pragma unroll
            for (int mm = 0; mm < 4; ++mm) {
                int m = m0 + tm * 4 + mm;
#pragma unroll
                for (int nn = 0; nn < 4; ++nn) {
                    int col = n0 + tn * 4 + nn;
                    if (col < 9 * C) Y[(size_t)m * (9 * C) + col] = acc[mm][nn];
                    else { int o = col - 9 * C; h[(size_t)m * C + o] = acc[mm][nn] + bias[o] + br[o]; }
                }
            }
        }
    }
}

// ---------------- phase: per-edge float4 gather + scatter-atomics ----------------
template<int C>
__device__ void egather_phase(
    const float* __restrict__ Y, const float* __restrict__ eattr,
    const int* __restrict__ ei, const float* __restrict__ deg,
    float* __restrict__ h)
{
    constexpr int Q = C / 4;
    for (int idx = blockIdx.x * NTHR + threadIdx.x; idx < NE * Q; idx += NBLK * NTHR) {
        int e = idx / Q;
        int q = idx - e * Q;
        int src = ei[e], dst = ei[NE + e];
        float d = deg[src];
        float nrm = d > 0.f ? 1.f / d : 0.f;
        const float4* y = (const float4*)(Y + (size_t)src * (9 * C));
        const float* ea = eattr + e * 8;
        float4 acc = y[8 * Q + q];      // be-term (ea'=1)
#pragma unroll
        for (int f = 0; f < 8; ++f) {
            float4 yf = y[f * Q + q];
            float w = ea[f];
            acc.x += w * yf.x; acc.y += w * yf.y; acc.z += w * yf.z; acc.w += w * yf.w;
        }
        float* hp = h + (size_t)dst * C + q * 4;
        atomicAdd(hp + 0, acc.x * nrm);
        atomicAdd(hp + 1, acc.y * nrm);
        atomicAdd(hp + 2, acc.z * nrm);
        atomicAdd(hp + 3, acc.w * nrm);
    }
}

// ---------------- phase: BN stats (sum / sumsq per channel) ----------------
template<int C>
__device__ void bnstat_phase(float* smem, const float* __restrict__ h, float* __restrict__ st)
{
    if (blockIdx.x < 64) {
        constexpr int NL = 256 / C;
        float* sred = smem;
        const int tid = threadIdx.x;
        const int o = tid % C, nl = tid / C;
        const int rbase = blockIdx.x * 64;
        float sum = 0.f, sq = 0.f;
        for (int r = nl; r < 64; r += NL) {
            float v = h[(size_t)(rbase + r) * C + o];
            sum += v; sq += v * v;
        }
        sred[tid] = sum;
        __syncthreads();
        if (tid < C) {
            float s = 0.f;
            for (int g2 = 0; g2 < NL; ++g2) s += sred[g2 * C + tid];
            atomicAdd(&st[tid], s);
        }
        __syncthreads();
        sred[tid] = sq;
        __syncthreads();
        if (tid < C) {
            float s = 0.f;
            for (int g2 = 0; g2 < NL; ++g2) s += sred[g2 * C + tid];
            atomicAdd(&st[C + tid], s);
        }
    }
}

// ---------------- phase: gated pooling (BN3+PReLU folded) ----------------
__device__ void pool_phase(float* smem,
    const float* __restrict__ h3, const int* __restrict__ batch,
    const float* __restrict__ st, const float* __restrict__ bg,
    const float* __restrict__ bb, const float* __restrict__ alpha,
    const float* __restrict__ Wi, const float* __restrict__ bi,
    const float* __restrict__ Wj, const float* __restrict__ bj,
    float* __restrict__ pooled)
{
    if (blockIdx.x >= NN / 16) return;
    constexpr int KN = 8, NB = 16;
    float* sH = smem;                  // 2048
    float* sS = smem + 2048;           // 128
    float* sT = smem + 2176;           // 128
    int*   sB = (int*)(smem + 2304);   // 16
    const int tid = threadIdx.x;
    const int nbase = blockIdx.x * NB;
    if (tid < 128) {
        float mean = st[tid] * (1.f / NN);
        float var  = st[128 + tid] * (1.f / NN) - mean * mean;
        var = fmaxf(var, 0.f);
        float s = rsqrtf(var + 1e-5f) * bg[tid];
        sS[tid] = s; sT[tid] = bb[tid] - mean * s;
    }
    float al = alpha[0];
    __syncthreads();
    for (int t = tid; t < NB * 128; t += NTHR) {
        int i = t % 128;
        float v = sS[i] * h3[(size_t)nbase * 128 + t] + sT[i];
        sH[t] = v >= 0.f ? v : al * v;
    }
    if (tid < NB) sB[tid] = batch[nbase + tid];
    __syncthreads();

    const int o = tid % 128, nl = tid / 128;
    float gacc[KN], facc[KN];
#pragma unroll
    for (int k = 0; k < KN; ++k) { gacc[k] = 0.f; facc[k] = 0.f; }
    for (int i = 0; i < 128; ++i) {
        float wi = Wi[i * 128 + o], wj = Wj[i * 128 + o];
#pragma unroll
        for (int k = 0; k < KN; ++k) {
            float hv = sH[(nl * KN + k) * 128 + i];
            gacc[k] += hv * wi;
            facc[k] += hv * wj;
        }
    }
    float bio = bi[o], bjo = bj[o];
#pragma unroll
    for (int k = 0; k < KN; ++k) {
        int r = nl * KN + k;
        float gate = 1.f / (1.f + expf(-(gacc[k] + bio)));
        float feat = tanhf(facc[k] + bjo);
        atomicAdd(&pooled[sB[r] * 128 + o], gate * feat);
    }
}

// ---------------- phase: final head ----------------
__device__ void final_phase(float* smem,
    const float* __restrict__ pooled, const float* __restrict__ Wfc,
    const float* __restrict__ bfc, float* __restrict__ out)
{
    if (blockIdx.x >= NG) return;
    float* sP = smem;
    const int g = blockIdx.x, c = threadIdx.x;
    if (c < 128) sP[c] = tanhf(pooled[g * 128 + c]);
    __syncthreads();
    float z = bfc[c];
    for (int i = 0; i < 128; ++i) z += sP[i] * Wfc[i * 256 + c];
    int oidx = (c < 128) ? (g * 128 + c) : (NG * 128 + g * 128 + (c - 128));
    out[oidx] = z;
}

// ---------------- the megakernel ----------------
__global__ __launch_bounds__(NTHR, 2) void k_mega(
    const float* __restrict__ x, const float* __restrict__ eattr,
    const int* __restrict__ ei, const int* __restrict__ batch,
    const float* We1, const float* be1, const float* bias1, const float* Wr1, const float* br1,
    const float* bg1, const float* bb1, const float* a1,
    const float* We2, const float* be2, const float* bias2, const float* Wr2, const float* br2,
    const float* bg2, const float* bb2, const float* a2,
    const float* We3, const float* be3, const float* bias3, const float* Wr3, const float* br3,
    const float* bg3, const float* bb3, const float* a3,
    const float* Wi, const float* bi, const float* Wj, const float* bj,
    const float* Wfc, const float* bfc,
    float* __restrict__ ws, float* __restrict__ out)
{
    __shared__ float smem[8832];   // 35.3 KB arena shared by all phases
    unsigned* bar = (unsigned*)(ws + OFF_BAR);

    prep_phase(We1, be1, Wr1, We2, be2, Wr2, We3, be3, Wr3, ei, ws);
    gsync(bar, 0);
    proj_phase<16, 32, false>(smem, x, ws + OFF_WX1, nullptr, nullptr, nullptr, nullptr,
                              bias1, br1, ws + OFF_Y, ws + OFF_H1);
    gsync(bar, 1);
    egather_phase<32>(ws + OFF_Y, eattr, ei, ws + OFF_DEG, ws + OFF_H1);
    gsync(bar, 2);
    bnstat_phase<32>(smem, ws + OFF_H1, ws + OFF_ST1);
    gsync(bar, 3);
    proj_phase<32, 64, true>(smem, ws + OFF_H1, ws + OFF_WX2, ws + OFF_ST1, bg1, bb1, a1,
                             bias2, br2, ws + OFF_Y, ws + OFF_H2);
    gsync(bar, 4);
    egather_phase<64>(ws + OFF_Y, eattr, ei, ws + OFF_DEG, ws + OFF_H2);
    gsync(bar, 5);
    bnstat_phase<64>(smem, ws + OFF_H2, ws + OFF_ST2);
    gsync(bar, 6);
    proj_phase<64, 128, true>(smem, ws + OFF_H2, ws + OFF_WX3, ws + OFF_ST2, bg2, bb2, a2,
                              bias3, br3, ws + OFF_Y, ws + OFF_H3);
    gsync(bar, 7);
    egather_phase<128>(ws + OFF_Y, eattr, ei, ws + OFF_DEG, ws + OFF_H3);
    gsync(bar, 8);
    bnstat_phase<128>(smem, ws + OFF_H3, ws + OFF_ST3);
    gsync(bar, 9);
    pool_phase(smem, ws + OFF_H3, batch, ws + OFF_ST3, bg3, bb3, a3, Wi, bi, Wj, bj, ws + OFF_POOL);
    gsync(bar, 10);
    final_phase(smem, ws + OFF_POOL, Wfc, bfc, out);
}

extern "C" void kernel_launch(void* const* d_in, const int* in_sizes, int n_in,
                              void* d_out, int out_size, void* d_ws, size_t ws_size,
                              hipStream_t stream)
{
    (void)in_sizes; (void)n_in; (void)out_size; (void)ws_size;
    const float* x     = (const float*)d_in[0];
    const float* eattr = (const float*)d_in[1];
    const int*   ei    = (const int*)d_in[2];
    const int*   batch = (const int*)d_in[3];
    const float* We1 = (const float*)d_in[4];
    const float* be1 = (const float*)d_in[5];
    const float* bias1 = (const float*)d_in[6];
    const float* Wr1 = (const float*)d_in[7];
    const float* br1 = (const float*)d_in[8];
    const float* bg1 = (const float*)d_in[9];
    const float* bb1 = (const float*)d_in[10];
    const float* a1  = (const float*)d_in[11];
    const float* We2 = (const float*)d_in[12];
    const float* be2 = (const float*)d_in[13];
    const float* bias2 = (const float*)d_in[14];
    const float* Wr2 = (const float*)d_in[15];
    const float* br2 = (const float*)d_in[16];
    const float* bg2 = (const float*)d_in[17];
    const float* bb2 = (const float*)d_in[18];
    const float* a2  = (const float*)d_in[19];
    const float* We3 = (const float*)d_in[20];
    const float* be3 = (const float*)d_in[21];
    const float* bias3 = (const float*)d_in[22];
    const float* Wr3 = (const float*)d_in[23];
    const float* br3 = (const float*)d_in[24];
    const float* bg3 = (const float*)d_in[25];
    const float* bb3 = (const float*)d_in[26];
    const float* a3  = (const float*)d_in[27];
    const float* Wi  = (const float*)d_in[28];
    const float* bi  = (const float*)d_in[29];
    const float* Wj  = (const float*)d_in[30];
    const float* bj  = (const float*)d_in[31];
    const float* Wfc = (const float*)d_in[32];
    const float* bfc = (const float*)d_in[33];
    float* ws  = (float*)d_ws;
    float* out = (float*)d_out;

    hipMemsetAsync(d_ws, 0, (size_t)ZERO_FLOATS * sizeof(float), stream);
    k_mega<<<NBLK, NTHR, 0, stream>>>(
        x, eattr, ei, batch,
        We1, be1, bias1, Wr1, br1, bg1, bb1, a1,
        We2, be2, bias2, Wr2, br2, bg2, bb2, a2,
        We3, be3, bias3, Wr3, br3, bg3, bb3, a3,
        Wi, bi, Wj, bj, Wfc, bfc, ws, out);
}

// Round 6
// 461.352 us; speedup vs baseline: 2.4796x; 1.5717x over previous
//
#include <hip/hip_runtime.h>
#include <math.h>

#define NN 4096
#define NE 16384
#define NG 64
#define NBLK 512
#define NTHR 256
#define GRP 64
#define NGRP (NBLK / GRP)   // 8 groups

// ---- ws layout (float offsets) ----
#define OFF_BAR   0        // 11 barriers x 17 x 32 uints = 5984 (round 6144)
#define OFF_DEG   6144     // 4096
#define OFF_ST1   10240    // 64
#define OFF_ST2   10304    // 128
#define OFF_ST3   10432    // 256
#define OFF_POOL  10688    // 8192
#define ZERO_FLOATS 18880  // zeroed by memset each call
#define OFF_H1    18880    // 4096*32
#define OFF_H2    149952   // 4096*64
#define OFF_H3    412096   // 4096*128
#define OFF_WX1   936384   // 16*320
#define OFF_WX2   941504   // 32*640
#define OFF_WX3   961984   // 64*1280
#define OFF_Y     1043904  // up to 4096*1152

// ---------------- two-level device-scope grid barrier ----------------
// R5 lesson: 512 waves RMW+polling ONE agent-scope line = ~54us/barrier
// (line-serialized RMWs + poll oversubscription). Split arrivals across 8
// group counters (128B-spaced), escalate to a master, broadcast 8 GO flags;
// each block polls only its group's flag (64 pollers/line, s_sleep backoff).
// Per-block release/acquire threadfence retained for cross-XCD visibility.
__device__ __forceinline__ void gsync(unsigned* bar, int idx) {
    __syncthreads();
    if (threadIdx.x == 0) {
        unsigned* base = bar + idx * 17 * 32;          // 17 lines of 32 uints
        const int g = blockIdx.x >> 6;                 // 64 blocks per group
        unsigned* gc = base + g * 32;
        unsigned* mc = base + 8 * 32;
        unsigned* go = base + (9 + g) * 32;
        __threadfence();   // release prior writes to agent scope
        unsigned r = __hip_atomic_fetch_add(gc, 1u, __ATOMIC_RELAXED, __HIP_MEMORY_SCOPE_AGENT);
        if (r == GRP - 1u) {                           // last in group
            unsigned m = __hip_atomic_fetch_add(mc, 1u, __ATOMIC_RELAXED, __HIP_MEMORY_SCOPE_AGENT);
            if (m == NGRP - 1u) {                      // global last: broadcast
                for (int k = 0; k < NGRP; ++k)
                    __hip_atomic_store(base + (9 + k) * 32, 1u,
                                       __ATOMIC_RELAXED, __HIP_MEMORY_SCOPE_AGENT);
            }
        }
        while (__hip_atomic_load(go, __ATOMIC_RELAXED, __HIP_MEMORY_SCOPE_AGENT) == 0u)
            __builtin_amdgcn_s_sleep(16);
        __threadfence();   // acquire side
    }
    __syncthreads();
}

// ---------------- phase: build Wext = [We | be | Wr] (K x 10C) + degree ----------------
__device__ __forceinline__ void build_wext(const float* We, const float* be,
                                           const float* Wr, float* Wx,
                                           int CIN, int C, int t) {
    int NC = 10 * C;
    int i = t / NC; int col = t - i * NC;
    float v;
    if (col < 8 * C)      { int f = col / C, o = col - f * C; v = We[f * CIN * C + o * CIN + i]; }
    else if (col < 9 * C) { int o = col - 8 * C;              v = be[o * CIN + i]; }
    else                  { int o = col - 9 * C;              v = Wr[i * C + o]; }
    Wx[t] = v;
}

__device__ void prep_phase(
    const float* We1, const float* be1, const float* Wr1,
    const float* We2, const float* be2, const float* Wr2,
    const float* We3, const float* be3, const float* Wr3,
    const int* ei, float* ws)
{
    int t = blockIdx.x * NTHR + threadIdx.x;
    if (t < 5120)  { build_wext(We1, be1, Wr1, ws + OFF_WX1, 16, 32, t); return; }
    t -= 5120;
    if (t < 20480) { build_wext(We2, be2, Wr2, ws + OFF_WX2, 32, 64, t); return; }
    t -= 20480;
    if (t < 81920) { build_wext(We3, be3, Wr3, ws + OFF_WX3, 64, 128, t); return; }
    t -= 81920;
    if (t < NE)    { atomicAdd(&ws[OFF_DEG + ei[t]], 1.0f); }
}

// ---------------- phase: proj GEMM [Y | h-init] = bn_prelu(A) @ [Wcat | Wr] ----------------
template<int K, int C, bool BN>
__device__ void proj_phase(float* smem,
    const float* __restrict__ A, const float* __restrict__ Bw,
    const float* __restrict__ st, const float* __restrict__ bg,
    const float* __restrict__ bb, const float* __restrict__ alpha,
    const float* __restrict__ bias, const float* __restrict__ br,
    float* __restrict__ Y, float* __restrict__ h)
{
    constexpr int NC = 10 * C;
    constexpr int TN = NC / 64;
    float* sA = smem;                 // [K][68]
    float* sB = smem + K * 68;        // [K][68]
    float* sS = smem + 2 * K * 68;    // [K]
    float* sT = sS + K;               // [K]
    const int tid = threadIdx.x;
    float al = BN ? alpha[0] : 0.f;

    if constexpr (BN) {
        if (tid < K) {
            float mean = st[tid] * (1.f / NN);
            float var  = st[K + tid] * (1.f / NN) - mean * mean;
            var = fmaxf(var, 0.f);
            float s = rsqrtf(var + 1e-5f) * bg[tid];
            sS[tid] = s; sT[tid] = bb[tid] - mean * s;
        }
    }

    for (int t = blockIdx.x; t < 64 * TN; t += NBLK) {
        __syncthreads();              // smem WAR across tiles/phases
        const int m0 = (t % 64) * 64;
        const int n0 = (t / 64) * 64;
        for (int u = tid; u < 64 * K; u += NTHR) {
            int m = u / K, i = u - m * K;
            float v = A[(m0 + m) * K + i];
            if constexpr (BN) { v = sS[i] * v + sT[i]; v = v >= 0.f ? v : al * v; }
            sA[i * 68 + m] = v;
        }
        for (int u = tid; u < 64 * K; u += NTHR) {
            int i = u / 64, n = u - i * 64;
            sB[i * 68 + n] = Bw[i * NC + n0 + n];
        }
        __syncthreads();

        const int tn = tid % 16, tm = tid / 16;
        float acc[4][4] = {{0.f}};
#pragma unroll 8
        for (int i = 0; i < K; ++i) {
            float4 a = *(const float4*)&sA[i * 68 + tm * 4];
            float4 b = *(const float4*)&sB[i * 68 + tn * 4];
            acc[0][0] += a.x * b.x; acc[0][1] += a.x * b.y; acc[0][2] += a.x * b.z; acc[0][3] += a.x * b.w;
            acc[1][0] += a.y * b.x; acc[1][1] += a.y * b.y; acc[1][2] += a.y * b.z; acc[1][3] += a.y * b.w;
            acc[2][0] += a.z * b.x; acc[2][1] += a.z * b.y; acc[2][2] += a.z * b.z; acc[2][3] += a.z * b.w;
            acc[3][0] += a.w * b.x; acc[3][1] += a.w * b.y; acc[3][2] += a.w * b.z; acc[3][3] += a.w * b.w;
        }

        if (n0 + 64 <= 9 * C) {            // pure-Y block
#pragma unroll
            for (int mm = 0; mm < 4; ++mm) {
                int m = m0 + tm * 4 + mm;
                float4 v = make_float4(acc[mm][0], acc[mm][1], acc[mm][2], acc[mm][3]);
                *(float4*)&Y[(size_t)m * (9 * C) + n0 + tn * 4] = v;
            }
        } else if (n0 >= 9 * C) {          // pure-residual block: init h
            int o = n0 - 9 * C + tn * 4;
            float4 add = *(const float4*)&bias[o];
            float4 ad2 = *(const float4*)&br[o];
#pragma unroll
            for (int mm = 0; mm < 4; ++mm) {
                int m = m0 + tm * 4 + mm;
                float4 v = make_float4(acc[mm][0] + add.x + ad2.x, acc[mm][1] + add.y + ad2.y,
                                       acc[mm][2] + add.z + ad2.z, acc[mm][3] + add.w + ad2.w);
                *(float4*)&h[(size_t)m * C + o] = v;
            }
        } else {                           // mixed block (C=32 only)
#pragma unroll
            for (int mm = 0; mm < 4; ++mm) {
                int m = m0 + tm * 4 + mm;
#pragma unroll
                for (int nn = 0; nn < 4; ++nn) {
                    int col = n0 + tn * 4 + nn;
                    if (col < 9 * C) Y[(size_t)m * (9 * C) + col] = acc[mm][nn];
                    else { int o = col - 9 * C; h[(size_t)m * C + o] = acc[mm][nn] + bias[o] + br[o]; }
                }
            }
        }
    }
}

// ---------------- phase: per-edge float4 gather + scatter-atomics ----------------
template<int C>
__device__ void egather_phase(
    const float* __restrict__ Y, const float* __restrict__ eattr,
    const int* __restrict__ ei, const float* __restrict__ deg,
    float* __restrict__ h)
{
    constexpr int Q = C / 4;
    for (int idx = blockIdx.x * NTHR + threadIdx.x; idx < NE * Q; idx += NBLK * NTHR) {
        int e = idx / Q;
        int q = idx - e * Q;
        int src = ei[e], dst = ei[NE + e];
        float d = deg[src];
        float nrm = d > 0.f ? 1.f / d : 0.f;
        const float4* y = (const float4*)(Y + (size_t)src * (9 * C));
        const float* ea = eattr + e * 8;
        float4 acc = y[8 * Q + q];      // be-term (ea'=1)
#pragma unroll
        for (int f = 0; f < 8; ++f) {
            float4 yf = y[f * Q + q];
            float w = ea[f];
            acc.x += w * yf.x; acc.y += w * yf.y; acc.z += w * yf.z; acc.w += w * yf.w;
        }
        float* hp = h + (size_t)dst * C + q * 4;
        atomicAdd(hp + 0, acc.x * nrm);
        atomicAdd(hp + 1, acc.y * nrm);
        atomicAdd(hp + 2, acc.z * nrm);
        atomicAdd(hp + 3, acc.w * nrm);
    }
}

// ---------------- phase: BN stats (sum / sumsq per channel) ----------------
template<int C>
__device__ void bnstat_phase(float* smem, const float* __restrict__ h, float* __restrict__ st)
{
    if (blockIdx.x < 64) {
        constexpr int NL = 256 / C;
        float* sred = smem;
        const int tid = threadIdx.x;
        const int o = tid % C, nl = tid / C;
        const int rbase = blockIdx.x * 64;
        float sum = 0.f, sq = 0.f;
        for (int r = nl; r < 64; r += NL) {
            float v = h[(size_t)(rbase + r) * C + o];
            sum += v; sq += v * v;
        }
        sred[tid] = sum;
        __syncthreads();
        if (tid < C) {
            float s = 0.f;
            for (int g2 = 0; g2 < NL; ++g2) s += sred[g2 * C + tid];
            atomicAdd(&st[tid], s);
        }
        __syncthreads();
        sred[tid] = sq;
        __syncthreads();
        if (tid < C) {
            float s = 0.f;
            for (int g2 = 0; g2 < NL; ++g2) s += sred[g2 * C + tid];
            atomicAdd(&st[C + tid], s);
        }
    }
}

// ---------------- phase: gated pooling (BN3+PReLU folded) ----------------
__device__ void pool_phase(float* smem,
    const float* __restrict__ h3, const int* __restrict__ batch,
    const float* __restrict__ st, const float* __restrict__ bg,
    const float* __restrict__ bb, const float* __restrict__ alpha,
    const float* __restrict__ Wi, const float* __restrict__ bi,
    const float* __restrict__ Wj, const float* __restrict__ bj,
    float* __restrict__ pooled)
{
    if (blockIdx.x >= NN / 16) return;
    constexpr int KN = 8, NB = 16;
    float* sH = smem;                  // 2048
    float* sS = smem + 2048;           // 128
    float* sT = smem + 2176;           // 128
    int*   sB = (int*)(smem + 2304);   // 16
    const int tid = threadIdx.x;
    const int nbase = blockIdx.x * NB;
    if (tid < 128) {
        float mean = st[tid] * (1.f / NN);
        float var  = st[128 + tid] * (1.f / NN) - mean * mean;
        var = fmaxf(var, 0.f);
        float s = rsqrtf(var + 1e-5f) * bg[tid];
        sS[tid] = s; sT[tid] = bb[tid] - mean * s;
    }
    float al = alpha[0];
    __syncthreads();
    for (int t = tid; t < NB * 128; t += NTHR) {
        int i = t % 128;
        float v = sS[i] * h3[(size_t)nbase * 128 + t] + sT[i];
        sH[t] = v >= 0.f ? v : al * v;
    }
    if (tid < NB) sB[tid] = batch[nbase + tid];
    __syncthreads();

    const int o = tid % 128, nl = tid / 128;
    float gacc[KN], facc[KN];
#pragma unroll
    for (int k = 0; k < KN; ++k) { gacc[k] = 0.f; facc[k] = 0.f; }
    for (int i = 0; i < 128; ++i) {
        float wi = Wi[i * 128 + o], wj = Wj[i * 128 + o];
#pragma unroll
        for (int k = 0; k < KN; ++k) {
            float hv = sH[(nl * KN + k) * 128 + i];
            gacc[k] += hv * wi;
            facc[k] += hv * wj;
        }
    }
    float bio = bi[o], bjo = bj[o];
#pragma unroll
    for (int k = 0; k < KN; ++k) {
        int r = nl * KN + k;
        float gate = 1.f / (1.f + expf(-(gacc[k] + bio)));
        float feat = tanhf(facc[k] + bjo);
        atomicAdd(&pooled[sB[r] * 128 + o], gate * feat);
    }
}

// ---------------- phase: final head ----------------
__device__ void final_phase(float* smem,
    const float* __restrict__ pooled, const float* __restrict__ Wfc,
    const float* __restrict__ bfc, float* __restrict__ out)
{
    if (blockIdx.x >= NG) return;
    float* sP = smem;
    const int g = blockIdx.x, c = threadIdx.x;
    if (c < 128) sP[c] = tanhf(pooled[g * 128 + c]);
    __syncthreads();
    float z = bfc[c];
    for (int i = 0; i < 128; ++i) z += sP[i] * Wfc[i * 256 + c];
    int oidx = (c < 128) ? (g * 128 + c) : (NG * 128 + g * 128 + (c - 128));
    out[oidx] = z;
}

// ---------------- the megakernel ----------------
__global__ __launch_bounds__(NTHR, 2) void k_mega(
    const float* __restrict__ x, const float* __restrict__ eattr,
    const int* __restrict__ ei, const int* __restrict__ batch,
    const float* We1, const float* be1, const float* bias1, const float* Wr1, const float* br1,
    const float* bg1, const float* bb1, const float* a1,
    const float* We2, const float* be2, const float* bias2, const float* Wr2, const float* br2,
    const float* bg2, const float* bb2, const float* a2,
    const float* We3, const float* be3, const float* bias3, const float* Wr3, const float* br3,
    const float* bg3, const float* bb3, const float* a3,
    const float* Wi, const float* bi, const float* Wj, const float* bj,
    const float* Wfc, const float* bfc,
    float* __restrict__ ws, float* __restrict__ out)
{
    __shared__ float smem[8832];   // 35.3 KB arena shared by all phases
    unsigned* bar = (unsigned*)(ws + OFF_BAR);

    prep_phase(We1, be1, Wr1, We2, be2, Wr2, We3, be3, Wr3, ei, ws);
    gsync(bar, 0);
    proj_phase<16, 32, false>(smem, x, ws + OFF_WX1, nullptr, nullptr, nullptr, nullptr,
                              bias1, br1, ws + OFF_Y, ws + OFF_H1);
    gsync(bar, 1);
    egather_phase<32>(ws + OFF_Y, eattr, ei, ws + OFF_DEG, ws + OFF_H1);
    gsync(bar, 2);
    bnstat_phase<32>(smem, ws + OFF_H1, ws + OFF_ST1);
    gsync(bar, 3);
    proj_phase<32, 64, true>(smem, ws + OFF_H1, ws + OFF_WX2, ws + OFF_ST1, bg1, bb1, a1,
                             bias2, br2, ws + OFF_Y, ws + OFF_H2);
    gsync(bar, 4);
    egather_phase<64>(ws + OFF_Y, eattr, ei, ws + OFF_DEG, ws + OFF_H2);
    gsync(bar, 5);
    bnstat_phase<64>(smem, ws + OFF_H2, ws + OFF_ST2);
    gsync(bar, 6);
    proj_phase<64, 128, true>(smem, ws + OFF_H2, ws + OFF_WX3, ws + OFF_ST2, bg2, bb2, a2,
                              bias3, br3, ws + OFF_Y, ws + OFF_H3);
    gsync(bar, 7);
    egather_phase<128>(ws + OFF_Y, eattr, ei, ws + OFF_DEG, ws + OFF_H3);
    gsync(bar, 8);
    bnstat_phase<128>(smem, ws + OFF_H3, ws + OFF_ST3);
    gsync(bar, 9);
    pool_phase(smem, ws + OFF_H3, batch, ws + OFF_ST3, bg3, bb3, a3, Wi, bi, Wj, bj, ws + OFF_POOL);
    gsync(bar, 10);
    final_phase(smem, ws + OFF_POOL, Wfc, bfc, out);
}

extern "C" void kernel_launch(void* const* d_in, const int* in_sizes, int n_in,
                              void* d_out, int out_size, void* d_ws, size_t ws_size,
                              hipStream_t stream)
{
    (void)in_sizes; (void)n_in; (void)out_size; (void)ws_size;
    const float* x     = (const float*)d_in[0];
    const float* eattr = (const float*)d_in[1];
    const int*   ei    = (const int*)d_in[2];
    const int*   batch = (const int*)d_in[3];
    const float* We1 = (const float*)d_in[4];
    const float* be1 = (const float*)d_in[5];
    const float* bias1 = (const float*)d_in[6];
    const float* Wr1 = (const float*)d_in[7];
    const float* br1 = (const float*)d_in[8];
    const float* bg1 = (const float*)d_in[9];
    const float* bb1 = (const float*)d_in[10];
    const float* a1  = (const float*)d_in[11];
    const float* We2 = (const float*)d_in[12];
    const float* be2 = (const float*)d_in[13];
    const float* bias2 = (const float*)d_in[14];
    const float* Wr2 = (const float*)d_in[15];
    const float* br2 = (const float*)d_in[16];
    const float* bg2 = (const float*)d_in[17];
    const float* bb2 = (const float*)d_in[18];
    const float* a2  = (const float*)d_in[19];
    const float* We3 = (const float*)d_in[20];
    const float* be3 = (const float*)d_in[21];
    const float* bias3 = (const float*)d_in[22];
    const float* Wr3 = (const float*)d_in[23];
    const float* br3 = (const float*)d_in[24];
    const float* bg3 = (const float*)d_in[25];
    const float* bb3 = (const float*)d_in[26];
    const float* a3  = (const float*)d_in[27];
    const float* Wi  = (const float*)d_in[28];
    const float* bi  = (const float*)d_in[29];
    const float* Wj  = (const float*)d_in[30];
    const float* bj  = (const float*)d_in[31];
    const float* Wfc = (const float*)d_in[32];
    const float* bfc = (const float*)d_in[33];
    float* ws  = (float*)d_ws;
    float* out = (float*)d_out;

    hipMemsetAsync(d_ws, 0, (size_t)ZERO_FLOATS * sizeof(float), stream);
    k_mega<<<NBLK, NTHR, 0, stream>>>(
        x, eattr, ei, batch,
        We1, be1, bias1, Wr1, br1, bg1, bb1, a1,
        We2, be2, bias2, Wr2, br2, bg2, bb2, a2,
        We3, be3, bias3, Wr3, br3, bg3, bb3, a3,
        Wi, bi, Wj, bj, Wfc, bfc, ws, out);
}

// Round 7
// 371.812 us; speedup vs baseline: 3.0767x; 1.2408x over previous
//
#include <hip/hip_runtime.h>
#include <math.h>

#define NN 4096
#define NE 16384
#define NG 64

// ---- ws layout (float offsets) ----
#define OFF_DEG   0         // 4096 floats (out-degree by src)
#define OFF_DCNT  4096      // 4096 ints (in-degree by dst)
#define OFF_ST1   8192      // 64
#define OFF_ST2   8256      // 128
#define OFF_ST3   8384      // 256
#define ZERO_FLOATS 8640    // zero deg/dcnt/stats only (34 KB)
#define OFF_OFFS  8704      // 4097 ints (CSR row offsets), rounded
#define OFF_LIST  12864     // 16384 ints (CSR edge ids)
#define OFF_H1    29248     // 4096*32
#define OFF_H2    160320    // 4096*64
#define OFF_H3    422464    // 4096*128
#define OFF_WX1   946752    // 16*320
#define OFF_WX2   951872    // 32*640
#define OFF_WX3   972352    // 64*1280
#define OFF_Y     1054272   // up to 4096*1152 (reused per layer)

// ---------------- prep: Wext = [We | be | Wr] + src-degree + dst-histogram ----------------
__device__ __forceinline__ void build_wext(const float* We, const float* be,
                                           const float* Wr, float* Wx,
                                           int CIN, int C, int t) {
    int NC = 10 * C;
    int i = t / NC; int col = t - i * NC;
    float v;
    if (col < 8 * C)      { int f = col / C, o = col - f * C; v = We[f * CIN * C + o * CIN + i]; }
    else if (col < 9 * C) { int o = col - 8 * C;              v = be[o * CIN + i]; }
    else                  { int o = col - 9 * C;              v = Wr[i * C + o]; }
    Wx[t] = v;
}

__global__ __launch_bounds__(256) void k_prep(
    const float* __restrict__ We1, const float* __restrict__ be1, const float* __restrict__ Wr1,
    const float* __restrict__ We2, const float* __restrict__ be2, const float* __restrict__ Wr2,
    const float* __restrict__ We3, const float* __restrict__ be3, const float* __restrict__ Wr3,
    const int* __restrict__ ei, float* __restrict__ ws)
{
    int t = blockIdx.x * 256 + threadIdx.x;
    if (t < 5120)  { build_wext(We1, be1, Wr1, ws + OFF_WX1, 16, 32, t); return; }
    t -= 5120;
    if (t < 20480) { build_wext(We2, be2, Wr2, ws + OFF_WX2, 32, 64, t); return; }
    t -= 20480;
    if (t < 81920) { build_wext(We3, be3, Wr3, ws + OFF_WX3, 64, 128, t); return; }
    t -= 81920;
    if (t < NE)    { atomicAdd(&ws[OFF_DEG + ei[t]], 1.0f); return; }
    t -= NE;
    if (t < NE)    { atomicAdd((int*)ws + OFF_DCNT + ei[NE + t], 1); }
}

// ---------------- CSR build (single block): prefix-scan + LDS-cursor scatter ----------------
__global__ __launch_bounds__(256) void k_csr(const int* __restrict__ ei, float* __restrict__ ws)
{
    __shared__ int cur[NN];     // 16 KB cursors
    __shared__ int part[256];
    int* dcnt = (int*)ws + OFF_DCNT;
    int* offs = (int*)ws + OFF_OFFS;
    int* list = (int*)ws + OFF_LIST;
    const int tid = threadIdx.x;
    const int base = tid * 16;
    int tmp[16]; int s = 0;
#pragma unroll
    for (int k = 0; k < 16; ++k) { tmp[k] = dcnt[base + k]; s += tmp[k]; }
    part[tid] = s;
    __syncthreads();
    if (tid == 0) { int run = 0; for (int i = 0; i < 256; ++i) { int v = part[i]; part[i] = run; run += v; } }
    __syncthreads();
    int run = part[tid];
#pragma unroll
    for (int k = 0; k < 16; ++k) { cur[base + k] = run; offs[base + k] = run; run += tmp[k]; }
    if (tid == 255) offs[NN] = run;
    __syncthreads();
    for (int e = tid; e < NE; e += 256) {
        int d = ei[NE + e];
        int pos = atomicAdd(&cur[d], 1);
        list[pos] = e;
    }
}

// ---------------- proj GEMM: [Y | h-init] = bn_prelu(A) @ [Wcat | Wr] ----------------
template<int K, int C, bool BN>
__global__ __launch_bounds__(256) void k_proj(
    const float* __restrict__ A, const float* __restrict__ Bw,
    const float* __restrict__ st, const float* __restrict__ bg,
    const float* __restrict__ bb, const float* __restrict__ alpha,
    const float* __restrict__ bias, const float* __restrict__ br,
    float* __restrict__ Y, float* __restrict__ h)
{
    constexpr int NC = 10 * C;
    __shared__ float sA[K][68];
    __shared__ float sB[K][68];
    __shared__ float sS[K], sT[K];
    const int tid = threadIdx.x;
    const int m0 = blockIdx.x * 64;
    const int n0 = blockIdx.y * 64;

    float al = 0.f;
    if constexpr (BN) {
        if (tid < K) {
            float mean = st[tid] * (1.f / NN);
            float var  = st[K + tid] * (1.f / NN) - mean * mean;
            var = fmaxf(var, 0.f);
            float s = rsqrtf(var + 1e-5f) * bg[tid];
            sS[tid] = s; sT[tid] = bb[tid] - mean * s;
        }
        al = alpha[0];
        __syncthreads();
    }
    for (int t = tid; t < 64 * K; t += 256) {
        int m = t / K, i = t - m * K;
        float v = A[(m0 + m) * K + i];
        if constexpr (BN) { v = sS[i] * v + sT[i]; v = v >= 0.f ? v : al * v; }
        sA[i][m] = v;
    }
    for (int t = tid; t < 64 * K; t += 256) {
        int i = t / 64, n = t - i * 64;
        sB[i][n] = Bw[i * NC + n0 + n];
    }
    __syncthreads();

    const int tn = tid % 16, tm = tid / 16;
    float acc[4][4] = {{0.f}};
#pragma unroll 8
    for (int i = 0; i < K; ++i) {
        float4 a = *(const float4*)&sA[i][tm * 4];
        float4 b = *(const float4*)&sB[i][tn * 4];
        acc[0][0] += a.x * b.x; acc[0][1] += a.x * b.y; acc[0][2] += a.x * b.z; acc[0][3] += a.x * b.w;
        acc[1][0] += a.y * b.x; acc[1][1] += a.y * b.y; acc[1][2] += a.y * b.z; acc[1][3] += a.y * b.w;
        acc[2][0] += a.z * b.x; acc[2][1] += a.z * b.y; acc[2][2] += a.z * b.z; acc[2][3] += a.z * b.w;
        acc[3][0] += a.w * b.x; acc[3][1] += a.w * b.y; acc[3][2] += a.w * b.z; acc[3][3] += a.w * b.w;
    }

    if (n0 + 64 <= 9 * C) {            // pure-Y block
#pragma unroll
        for (int mm = 0; mm < 4; ++mm) {
            int m = m0 + tm * 4 + mm;
            float4 v = make_float4(acc[mm][0], acc[mm][1], acc[mm][2], acc[mm][3]);
            *(float4*)&Y[(size_t)m * (9 * C) + n0 + tn * 4] = v;
        }
    } else if (n0 >= 9 * C) {          // pure-residual block: init h = resid + bias + br
        int o = n0 - 9 * C + tn * 4;
        float4 add = *(const float4*)&bias[o];
        float4 ad2 = *(const float4*)&br[o];
#pragma unroll
        for (int mm = 0; mm < 4; ++mm) {
            int m = m0 + tm * 4 + mm;
            float4 v = make_float4(acc[mm][0] + add.x + ad2.x, acc[mm][1] + add.y + ad2.y,
                                   acc[mm][2] + add.z + ad2.z, acc[mm][3] + add.w + ad2.w);
            *(float4*)&h[(size_t)m * C + o] = v;
        }
    } else {                           // mixed block (C=32 only)
#pragma unroll
        for (int mm = 0; mm < 4; ++mm) {
            int m = m0 + tm * 4 + mm;
#pragma unroll
            for (int nn = 0; nn < 4; ++nn) {
                int col = n0 + tn * 4 + nn;
                if (col < 9 * C) Y[(size_t)m * (9 * C) + col] = acc[mm][nn];
                else { int o = col - 9 * C; h[(size_t)m * C + o] = acc[mm][nn] + bias[o] + br[o]; }
            }
        }
    }
}

// ---------------- enode: CSR gather (no atomics on h) + residual + BN stats ----------------
template<int C>
__global__ __launch_bounds__(256) void k_enode(
    const float* __restrict__ Y, const float* __restrict__ eattr,
    const int* __restrict__ ei, const float* __restrict__ deg,
    const int* __restrict__ offs, const int* __restrict__ list,
    float* __restrict__ h, float* __restrict__ st)
{
    constexpr int NL = 256 / C;
    __shared__ float sred[256];
    const int tid = threadIdx.x;
    const int o = tid % C, nl = tid / C;
    const int n0 = blockIdx.x * 16;
    float sum = 0.f, sq = 0.f;
    for (int r = nl; r < 16; r += NL) {
        const int n = n0 + r;
        const int e0 = offs[n], e1 = offs[n + 1];
        float acc = h[(size_t)n * C + o];       // resid + bias + br from proj
        for (int e = e0; e < e1; ++e) {
            const int eid = list[e];
            const int src = ei[eid];
            const float nrm = 1.f / deg[src];   // deg>=1: src has at least this edge
            const float* y = Y + (size_t)src * (9 * C);
            const float* ea = eattr + eid * 8;
            float a = y[8 * C + o];             // be-term (ea'=1)
#pragma unroll
            for (int f = 0; f < 8; ++f) a += ea[f] * y[f * C + o];
            acc += a * nrm;
        }
        h[(size_t)n * C + o] = acc;
        sum += acc; sq += acc * acc;
    }
    sred[tid] = sum;
    __syncthreads();
    if (tid < C) {
        float s = 0.f;
        for (int l = 0; l < NL; ++l) s += sred[l * C + tid];
        atomicAdd(&st[tid], s);
    }
    __syncthreads();
    sred[tid] = sq;
    __syncthreads();
    if (tid < C) {
        float s = 0.f;
        for (int l = 0; l < NL; ++l) s += sred[l * C + tid];
        atomicAdd(&st[C + tid], s);
    }
}

// ---------------- pool+final fused: per-graph block, no atomics ----------------
__global__ __launch_bounds__(256) void k_poolfinal(
    const float* __restrict__ h3, const int* __restrict__ batch,
    const float* __restrict__ st, const float* __restrict__ bg,
    const float* __restrict__ bb, const float* __restrict__ alpha,
    const float* __restrict__ Wi, const float* __restrict__ bi,
    const float* __restrict__ Wj, const float* __restrict__ bj,
    const float* __restrict__ Wfc, const float* __restrict__ bfc,
    float* __restrict__ out)
{
    __shared__ float sS[128], sT[128];
    __shared__ float sH[8][128];
    __shared__ float sG[8][128];
    __shared__ float sP[128];
    const int g = blockIdx.x, tid = threadIdx.x;
    if (tid < 128) {
        float mean = st[tid] * (1.f / NN);
        float var  = st[128 + tid] * (1.f / NN) - mean * mean;
        var = fmaxf(var, 0.f);
        float s = rsqrtf(var + 1e-5f) * bg[tid];
        sS[tid] = s; sT[tid] = bb[tid] - mean * s;
    }
    const float al = alpha[0];
    // batch is sorted: binary-search this graph's node range
    int a = 0, b = NN;
    while (a < b) { int m = (a + b) >> 1; if (batch[m] < g) a = m + 1; else b = m; }
    const int ns = a;
    a = 0; b = NN;
    while (a < b) { int m = (a + b) >> 1; if (batch[m] <= g) a = m + 1; else b = m; }
    const int ne = a;
    __syncthreads();

    const int o = tid & 127, w = tid >> 7;          // w=0: gate dot, w=1: feat dot
    const float* Wg = w ? Wj : Wi;
    const float bo = w ? bj[o] : bi[o];
    float accP = 0.f;
    for (int c0 = ns; c0 < ne; c0 += 8) {
        const int cs = min(8, ne - c0);
        __syncthreads();                            // sH/sG WAR
        for (int u = tid; u < cs * 128; u += 256) {
            int k = u >> 7, i = u & 127;
            float v = sS[i] * h3[(size_t)(c0 + k) * 128 + i] + sT[i];
            sH[k][i] = v >= 0.f ? v : al * v;
        }
        __syncthreads();
        float d[8];
#pragma unroll
        for (int k = 0; k < 8; ++k) d[k] = 0.f;
        for (int i = 0; i < 128; ++i) {
            float wv = Wg[i * 128 + o];
#pragma unroll
            for (int k = 0; k < 8; ++k) d[k] += sH[k][i] * wv;
        }
        if (w == 0) for (int k = 0; k < cs; ++k) sG[k][o] = 1.f / (1.f + expf(-(d[k] + bo)));
        __syncthreads();
        if (w == 1) for (int k = 0; k < cs; ++k) accP += sG[k][o] * tanhf(d[k] + bo);
    }
    __syncthreads();
    if (w == 1) sP[o] = tanhf(accP);
    __syncthreads();
    float z = bfc[tid];
    for (int i = 0; i < 128; ++i) z += sP[i] * Wfc[i * 256 + tid];
    const int oidx = (tid < 128) ? g * 128 + tid : NG * 128 + g * 128 + (tid - 128);
    out[oidx] = z;
}

extern "C" void kernel_launch(void* const* d_in, const int* in_sizes, int n_in,
                              void* d_out, int out_size, void* d_ws, size_t ws_size,
                              hipStream_t stream)
{
    (void)in_sizes; (void)n_in; (void)out_size; (void)ws_size;
    const float* x     = (const float*)d_in[0];
    const float* eattr = (const float*)d_in[1];
    const int*   ei    = (const int*)d_in[2];
    const int*   batch = (const int*)d_in[3];
    const float* We1 = (const float*)d_in[4];
    const float* be1 = (const float*)d_in[5];
    const float* bias1 = (const float*)d_in[6];
    const float* Wr1 = (const float*)d_in[7];
    const float* br1 = (const float*)d_in[8];
    const float* bg1 = (const float*)d_in[9];
    const float* bb1 = (const float*)d_in[10];
    const float* a1  = (const float*)d_in[11];
    const float* We2 = (const float*)d_in[12];
    const float* be2 = (const float*)d_in[13];
    const float* bias2 = (const float*)d_in[14];
    const float* Wr2 = (const float*)d_in[15];
    const float* br2 = (const float*)d_in[16];
    const float* bg2 = (const float*)d_in[17];
    const float* bb2 = (const float*)d_in[18];
    const float* a2  = (const float*)d_in[19];
    const float* We3 = (const float*)d_in[20];
    const float* be3 = (const float*)d_in[21];
    const float* bias3 = (const float*)d_in[22];
    const float* Wr3 = (const float*)d_in[23];
    const float* br3 = (const float*)d_in[24];
    const float* bg3 = (const float*)d_in[25];
    const float* bb3 = (const float*)d_in[26];
    const float* a3  = (const float*)d_in[27];
    const float* Wi  = (const float*)d_in[28];
    const float* bi  = (const float*)d_in[29];
    const float* Wj  = (const float*)d_in[30];
    const float* bj  = (const float*)d_in[31];
    const float* Wfc = (const float*)d_in[32];
    const float* bfc = (const float*)d_in[33];
    float* ws  = (float*)d_ws;
    float* out = (float*)d_out;
    const int* offs = (const int*)ws + OFF_OFFS;
    const int* list = (const int*)ws + OFF_LIST;

    hipMemsetAsync(d_ws, 0, (size_t)ZERO_FLOATS * sizeof(float), stream);
    k_prep<<<548, 256, 0, stream>>>(We1, be1, Wr1, We2, be2, Wr2, We3, be3, Wr3, ei, ws);
    k_csr<<<1, 256, 0, stream>>>(ei, ws);

    // layer 1: K=16, C=32
    k_proj<16, 32, false><<<dim3(64, 5), 256, 0, stream>>>(
        x, ws + OFF_WX1, nullptr, nullptr, nullptr, nullptr, bias1, br1, ws + OFF_Y, ws + OFF_H1);
    k_enode<32><<<NN / 16, 256, 0, stream>>>(ws + OFF_Y, eattr, ei, ws + OFF_DEG, offs, list,
                                             ws + OFF_H1, ws + OFF_ST1);
    // layer 2: K=32, C=64
    k_proj<32, 64, true><<<dim3(64, 10), 256, 0, stream>>>(
        ws + OFF_H1, ws + OFF_WX2, ws + OFF_ST1, bg1, bb1, a1, bias2, br2, ws + OFF_Y, ws + OFF_H2);
    k_enode<64><<<NN / 16, 256, 0, stream>>>(ws + OFF_Y, eattr, ei, ws + OFF_DEG, offs, list,
                                             ws + OFF_H2, ws + OFF_ST2);
    // layer 3: K=64, C=128
    k_proj<64, 128, true><<<dim3(64, 20), 256, 0, stream>>>(
        ws + OFF_H2, ws + OFF_WX3, ws + OFF_ST2, bg2, bb2, a2, bias3, br3, ws + OFF_Y, ws + OFF_H3);
    k_enode<128><<<NN / 16, 256, 0, stream>>>(ws + OFF_Y, eattr, ei, ws + OFF_DEG, offs, list,
                                              ws + OFF_H3, ws + OFF_ST3);
    // pool + head (BN3 folded), per-graph blocks, no atomics
    k_poolfinal<<<NG, 256, 0, stream>>>(ws + OFF_H3, batch, ws + OFF_ST3, bg3, bb3, a3,
                                        Wi, bi, Wj, bj, Wfc, bfc, out);
}